// Round 6
// baseline (461.863 us; speedup 1.0000x reference)
//
#include <hip/hip_runtime.h>
#include <stdint.h>

// Fused MLP decode, MFMA f16. ROUND 6: ABLATION ROUND.
// R5 lesson: launch_bounds(,4) + 24 extra const regs -> per-iter scratch
// spills (WRITE_SIZE 7.8->27.6 MB), dur 106->127. Fix here: (256,3).
// R3-R5 mystery: per-wave-iteration latency ~5200 cyc but enumerable
// stalls sum to ~1000. This round dispatches 5 FULL-WORKLOAD template
// variants (same grid) to name the stall; the CORRECT variant runs LAST
// and overwrites d_out (stream-ordered), so the bench stays correct.
// Headline dur_us is ~5x this round by design.
//   <1> NOMEM   : tix/rho/emb synthesized (no global loads at all)
//   <2> NOEMB   : real tix/rho, emb synthesized
//   <3> NODS    : H writes kept, Y fed from registers (no DS RAW wait)
//   <4> NOTRANS : sin/cos/exp2/rcp replaced by fma/mul (no trans pipe)
//   <0> FULL    : correct kernel (R5 swapped-L1 structure, no spills)
// Keepalive discipline (rule #17): ablated stages still feed the store.

typedef _Float16 half8  __attribute__((ext_vector_type(8)));
typedef _Float16 half4v __attribute__((ext_vector_type(4)));
typedef _Float16 half2v __attribute__((ext_vector_type(2)));
typedef float f32x4 __attribute__((ext_vector_type(4)));

#define LOG2E 1.44269504088896340736f
#define NLN2  -0.6931471805599453f         // -ln2 = 1/(-log2e)
#define CSCL  -1.44269504088896340736f     // c = -log2e
#define BASE_LOGIT -0.84729786038720367f   // log(0.3/0.7)
#define CSANMAX 28700.0f
#define IC_VAL 8610.0f                     // 0.3 * 28700

__device__ __forceinline__ float fast_exp2(float x) { return __builtin_amdgcn_exp2f(x); }
__device__ __forceinline__ float fast_rcp(float x)  { return __builtin_amdgcn_rcpf(x); }
__device__ __forceinline__ half2v pkh(float a, float b) {
  return __builtin_bit_cast(half2v, __builtin_amdgcn_cvt_pkrtz(a, b));
}

union H8 { half8 v8; half2v v2[4]; half4v v4[2]; };
union H4 { half4v v4; half2v v2[2]; };

template <int V>
__global__ __launch_bounds__(256, 3) void mlp_kernel(
    const int* __restrict__ tix, const float* __restrict__ rho,
    const float* __restrict__ emb, const float* __restrict__ W0,
    const float* __restrict__ b0, const float* __restrict__ W1,
    const float* __restrict__ b1, const float* __restrict__ Wout,
    const float* __restrict__ bout, float* __restrict__ out, int ntiles)
{
  constexpr bool TIXR = (V != 1);              // real tix/rho loads
  constexpr bool EMBR = (V != 1) && (V != 2);  // real emb gather
  constexpr bool DSR  = (V != 3);              // real DS RAW round trip
  constexpr bool TRR  = (V != 4);              // real transcendentals

  // Weight staging (init only, both layers) overlaps the per-wave H buffer.
  __shared__ __align__(16) union {
    _Float16 stage[2][2][4][64][8];
    _Float16 H[4][16][72];          // per-wave H (stride 144 B, 2-way banks)
  } shA;

  const int tid  = threadIdx.x;
  const int wid  = tid >> 6;
  const int lane = tid & 63;
  const int m    = lane & 15;
  const int q    = lane >> 4;

  _Float16 (*Hb)[72] = shA.H[wid];

  // ---- init: wave 0 builds the swizzled weight fragments ----
  if (wid == 0) {
#pragma unroll
    for (int t = 0; t < 4; ++t) {
#pragma unroll
      for (int s = 0; s < 2; ++s) {
        half8 f0, f1;
#pragma unroll
        for (int j = 0; j < 8; ++j) {
          const int k = s * 32 + q * 8 + j;
          const int n = t * 16 + m;
          float v0;
          if (k < 32) {
            v0 = W0[k * 64 + n];
          } else {
            const int kn = k - 32;
            v0 = (kn < 16) ? W0[(33 + kn) * 64 + n]
               : (kn == 16) ? W0[32 * 64 + n]
               : (kn == 17) ? b0[n] : 0.0f;
          }
          f0[j] = (_Float16)(CSCL * v0);
          f1[j] = (_Float16)W1[k * 64 + n];   // W1 UNSCALED (c rides through p)
        }
        *(half8*)&shA.stage[0][s][t][lane][0] = f0;
        *(half8*)&shA.stage[1][s][t][lane][0] = f1;
      }
    }
  }

  // ---- persistent epilogue constants (SWAPPED L1 layout) ----
  // lane (q,m) owns hidden h = t*16 + q*4 + r.
  f32x4 bq1acc[4];
  f32x4 woutq[4];
#pragma unroll
  for (int t = 0; t < 4; ++t) {
    const f32x4 bv = *(const f32x4*)(b1 + t * 16 + q * 4);
    const f32x4 wv = *(const f32x4*)(Wout + t * 16 + q * 4);
#pragma unroll
    for (int r = 0; r < 4; ++r) {
      bq1acc[t][r] = CSCL * bv[r];
      woutq[t][r]  = NLN2 * wv[r];
    }
  }
  const float boutBL = bout[0] + BASE_LOGIT;

  __syncthreads();   // staged weights visible

  half8 w0A[4], w0B[4], w1A[4], w1B[4];
#pragma unroll
  for (int t = 0; t < 4; ++t) {
    w0A[t] = *(const half8*)&shA.stage[0][0][t][lane][0];
    w0B[t] = *(const half8*)&shA.stage[0][1][t][lane][0];
    w1A[t] = *(const half8*)&shA.stage[1][0][t][lane][0];
    w1B[t] = *(const half8*)&shA.stage[1][1][t][lane][0];
  }

  __syncthreads();   // stage reads done; H may overwrite

  const f32x4 z = {0.0f, 0.0f, 0.0f, 0.0f};
  const int tstride = gridDim.x * 4;

  int tg = blockIdx.x * 4 + wid;
  if (tg >= ntiles) return;
  const int lim = ntiles - 1;

  // ---- pipeline preload ----
  int   t0, t1;
  float r0, r1;
  if constexpr (TIXR) {
    t0 = tix[tg * 16 + m];
    r0 = rho[tg * 16 + m];
    const int tg1 = min(tg + tstride, lim);
    t1 = tix[tg1 * 16 + m];
    r1 = rho[tg1 * 16 + m];
  } else {
    t0 = ((tg + m * 13) & 255) + 1;
    r0 = (float)((tg + m * 7) & 127) * 0.0078125f;
    t1 = ((tg + tstride + m * 13) & 255) + 1;
    r1 = (float)((tg + tstride + m * 7) & 127) * 0.0078125f;
  }
  f32x4 eC0, eC1;
  if constexpr (EMBR) {
    const int idx0 = min(max(t0 - 1, 0), 510);
    const float* er0 = emb + (size_t)idx0 * 32 + q * 8;
    eC0 = *(const f32x4*)er0;
    eC1 = *(const f32x4*)(er0 + 4);
  } else {
    const float b = (float)t0 * 0.003f + (float)q * 0.01f;
    eC0 = (f32x4){b, b + 0.1f, b + 0.2f, b + 0.3f};
    eC1 = (f32x4){b + 0.4f, b + 0.5f, b + 0.6f, b + 0.7f};
  }

  while (true) {
    // ---- prefetch: tix/rho 2 tiles ahead ----
    int   t2;
    float r2;
    if constexpr (TIXR) {
      const int tg2 = min(tg + 2 * tstride, lim);
      t2 = tix[tg2 * 16 + m];
      r2 = rho[tg2 * 16 + m];
    } else {
      t2 = ((tg + 2 * tstride + m * 13) & 255) + 1;
      r2 = (float)((tg + 2 * tstride + m * 7) & 127) * 0.0078125f;
    }
    // ---- prefetch: emb 1 tile ahead ----
    f32x4 eN0, eN1;
    if constexpr (EMBR) {
      const int idxN = min(max(t1 - 1, 0), 510);
      const float* ern = emb + (size_t)idxN * 32 + q * 8;
      eN0 = *(const f32x4*)ern;
      eN1 = *(const f32x4*)(ern + 4);
    } else {
      const float b = (float)t1 * 0.003f + (float)q * 0.01f;
      eN0 = (f32x4){b, b + 0.1f, b + 0.2f, b + 0.3f};
      eN1 = (f32x4){b + 0.4f, b + 0.5f, b + 0.6f, b + 0.7f};
    }

    // ---- feature fragment (Chebyshev chain) ----
    const float rhp = r0;
    const float rev = 0.5f * rhp;
    float c1, s1f;
    if constexpr (TRR) {
      c1  = __builtin_amdgcn_cosf(rev);
      s1f = __builtin_amdgcn_sinf(rev);
    } else {
      c1  = fmaf(rev, -0.5f, 1.0f);   // fake, VALU-only
      s1f = rev * 0.8f;
    }
    const float tc  = 2.0f * c1;
    const float x1v = (q == 0) ? c1 : ((q == 1) ? s1f : 0.0f);
    const float x0v = (q == 0) ? 1.0f : 0.0f;
    const float x2v = tc * x1v - x0v;
    const float x3v = tc * x2v - x1v;
    const float x4v = tc * x3v - x2v;
    const float x5v = tc * x4v - x3v;
    const float x6v = tc * x5v - x4v;
    const float x7v = tc * x6v - x5v;
    const float x8v = tc * x7v - x6v;
    H8 X1;
    X1.v2[0] = (q == 2) ? pkh(rhp, 1.0f) : pkh(x1v, x2v);
    X1.v2[1] = pkh(x3v, x4v);
    X1.v2[2] = pkh(x5v, x6v);
    X1.v2[3] = pkh(x7v, x8v);
    H8 X0;
    X0.v2[0] = pkh(eC0[0], eC0[1]); X0.v2[1] = pkh(eC0[2], eC0[3]);
    X0.v2[2] = pkh(eC1[0], eC1[1]); X0.v2[3] = pkh(eC1[2], eC1[3]);

    // ---- L0 (A=W0^T, B=X): u = c*preact0, layout [hidden][point] ----
    f32x4 acc[4];
#pragma unroll
    for (int t = 0; t < 4; ++t) {
      f32x4 a = __builtin_amdgcn_mfma_f32_16x16x32_f16(w0A[t], X0.v8, z, 0, 0, 0);
      a = __builtin_amdgcn_mfma_f32_16x16x32_f16(w0B[t], X1.v8, a, 0, 0, 0);
      acc[t] = a;
    }
    // epilogue: p = u*sigma -> f16 -> H
    H4 hh[4];
#pragma unroll
    for (int t = 0; t < 4; ++t) {
      float p0, p1, p2, p3;
      if constexpr (TRR) {
        const float d0 = 1.0f + fast_exp2(acc[t][0]);
        const float d1 = 1.0f + fast_exp2(acc[t][1]);
        const float d2 = 1.0f + fast_exp2(acc[t][2]);
        const float d3 = 1.0f + fast_exp2(acc[t][3]);
        const float rA = fast_rcp(d0 * d1);
        const float rB = fast_rcp(d2 * d3);
        p0 = acc[t][0] * d1 * rA;  p1 = acc[t][1] * d0 * rA;
        p2 = acc[t][2] * d3 * rB;  p3 = acc[t][3] * d2 * rB;
      } else {
        p0 = acc[t][0] * 0.25f;  p1 = acc[t][1] * 0.25f;
        p2 = acc[t][2] * 0.25f;  p3 = acc[t][3] * 0.25f;
      }
      hh[t].v2[0] = pkh(p0, p1);
      hh[t].v2[1] = pkh(p2, p3);
      *(half4v*)&Hb[m][t * 16 + q * 4] = hh[t].v4;   // write kept in ALL variants
    }

    // ---- L1 SWAPPED (A=W1^T, B=H^T): acc=[hidden][point], C=c*b1 ----
    half8 Y0, Y1;
    if constexpr (DSR) {
      Y0 = *(const half8*)&Hb[m][q * 8];        // in-order DS: RAW safe
      Y1 = *(const half8*)&Hb[m][32 + q * 8];
    } else {
      H8 y0, y1;                                 // register feed (wrong math, alive)
      y0.v4[0] = hh[0].v4; y0.v4[1] = hh[1].v4;
      y1.v4[0] = hh[2].v4; y1.v4[1] = hh[3].v4;
      Y0 = y0.v8; Y1 = y1.v8;
    }
#pragma unroll
    for (int t = 0; t < 4; ++t) {
      f32x4 a = __builtin_amdgcn_mfma_f32_16x16x32_f16(w1A[t], Y0, bq1acc[t], 0, 0, 0);
      a = __builtin_amdgcn_mfma_f32_16x16x32_f16(w1B[t], Y1, a, 0, 0, 0);
      acc[t] = a;
    }
    // per-lane 16-h partial dot; 2 shfl_xor to finish
    float dA = 0.0f, dB = 0.0f;
#pragma unroll
    for (int t = 0; t < 4; ++t) {
      float p0, p1, p2, p3;
      if constexpr (TRR) {
        const float d0 = 1.0f + fast_exp2(acc[t][0]);
        const float d1 = 1.0f + fast_exp2(acc[t][1]);
        const float d2 = 1.0f + fast_exp2(acc[t][2]);
        const float d3 = 1.0f + fast_exp2(acc[t][3]);
        const float rA = fast_rcp(d0 * d1);
        const float rB = fast_rcp(d2 * d3);
        p0 = acc[t][0] * d1 * rA;  p1 = acc[t][1] * d0 * rA;
        p2 = acc[t][2] * d3 * rB;  p3 = acc[t][3] * d2 * rB;
      } else {
        p0 = acc[t][0] * 0.25f;  p1 = acc[t][1] * 0.25f;
        p2 = acc[t][2] * 0.25f;  p3 = acc[t][3] * 0.25f;
      }
      dA = fmaf(p0, woutq[t][0], dA);
      dB = fmaf(p1, woutq[t][1], dB);
      dA = fmaf(p2, woutq[t][2], dA);
      dB = fmaf(p3, woutq[t][3], dB);
    }
    float dot = dA + dB;
    dot += __shfl_xor(dot, 16, 64);
    dot += __shfl_xor(dot, 32, 64);

    // ---- epilogue ----
    float theta;
    if constexpr (TRR) {
      theta = fast_rcp(1.0f + fast_exp2(-LOG2E * (dot + boutBL)));
    } else {
      theta = fmaf(dot + boutBL, 0.01f, 0.5f);
    }
    const float val = (t0 == 0) ? IC_VAL : theta * CSANMAX;
    if (q == 0) out[tg * 16 + m] = val;

    // ---- advance pipeline ----
    const int tgn = tg + tstride;
    if (tgn >= ntiles) break;
    tg = tgn;
    t0 = t1; r0 = r1;
    t1 = t2; r1 = r2;
    eC0 = eN0; eC1 = eN1;
  }
}

extern "C" void kernel_launch(void* const* d_in, const int* in_sizes, int n_in,
                              void* d_out, int out_size, void* d_ws, size_t ws_size,
                              hipStream_t stream) {
  const int*   tix  = (const int*)d_in[0];
  const float* rho  = (const float*)d_in[1];
  const float* emb  = (const float*)d_in[2];
  const float* W0   = (const float*)d_in[3];
  const float* b0   = (const float*)d_in[4];
  const float* W1   = (const float*)d_in[5];
  const float* b1   = (const float*)d_in[6];
  const float* Wout = (const float*)d_in[7];
  const float* bout = (const float*)d_in[8];
  float* outp = (float*)d_out;

  const int n      = in_sizes[0];    // 2,000,000 (divisible by 16)
  const int ntiles = n / 16;         // 125,000 tiles of 16 points

  int grid = 1024;
  const int maxg = (ntiles + 3) / 4;
  if (grid > maxg) grid = maxg;

  // Ablation dispatches (garbage output, full workload each), then the
  // CORRECT kernel LAST overwrites every output element (same store map).
  mlp_kernel<1><<<dim3(grid), dim3(256), 0, stream>>>(tix, rho, emb, W0, b0, W1, b1, Wout, bout, outp, ntiles); // NOMEM
  mlp_kernel<2><<<dim3(grid), dim3(256), 0, stream>>>(tix, rho, emb, W0, b0, W1, b1, Wout, bout, outp, ntiles); // NOEMB
  mlp_kernel<3><<<dim3(grid), dim3(256), 0, stream>>>(tix, rho, emb, W0, b0, W1, b1, Wout, bout, outp, ntiles); // NODS
  mlp_kernel<4><<<dim3(grid), dim3(256), 0, stream>>>(tix, rho, emb, W0, b0, W1, b1, Wout, bout, outp, ntiles); // NOTRANS
  mlp_kernel<0><<<dim3(grid), dim3(256), 0, stream>>>(tix, rho, emb, W0, b0, W1, b1, Wout, bout, outp, ntiles); // FULL (correct)
}

// Round 7
// 159.973 us; speedup vs baseline: 2.8871x; 2.8871x over previous
//
#include <hip/hip_runtime.h>
#include <stdint.h>

// Fused MLP decode, MFMA f16. ROUND 7: MODULO-2 SOFTWARE PIPELINE.
// R6 ablation verdict: removing global-mem / emb / DS-RAW / trans each
// changes little (DS: nothing; mem <=20%; trans <=15%) -> the limiter is
// the per-tile serial chain feat->L0->silu->H->L1->silu->dot at 2-3
// waves/SIMD. Fix: rotate the loop. Iteration k runs
//   phase2(tile k-1): Y-read(H[b^1]) -> L1 -> silu -> dot -> store
//   phase1(tile k)  : feat -> L0 -> silu -> H-write(H[b])
// The two phases are INDEPENDENT tiles -> scheduler interleaves the two
// chains (the R0 4-subtile kernel could not: its subtiles serialized
// through ONE H buffer). H double-buffered per wave; Y reads target data
// written a full iteration ago (DS RAW slack ~2000cy). Carried state is
// tiny: packed emb frag (4 regs) + pipeline scalars.
// Structure otherwise = R6-V0 (passed): swapped L1 (mfma(w1,Y)), b1 as
// MFMA C-operand, per-lane Wout dot + 2 shfl_xor, scale-folded u-domain
// silu, Chebyshev feature chain, weights AGPR-resident.

typedef _Float16 half8  __attribute__((ext_vector_type(8)));
typedef _Float16 half4v __attribute__((ext_vector_type(4)));
typedef _Float16 half2v __attribute__((ext_vector_type(2)));
typedef float f32x4 __attribute__((ext_vector_type(4)));

#define LOG2E 1.44269504088896340736f
#define NLN2  -0.6931471805599453f         // -ln2 = 1/(-log2e)
#define CSCL  -1.44269504088896340736f     // c = -log2e
#define BASE_LOGIT -0.84729786038720367f   // log(0.3/0.7)
#define CSANMAX 28700.0f
#define IC_VAL 8610.0f                     // 0.3 * 28700

__device__ __forceinline__ float fast_exp2(float x) { return __builtin_amdgcn_exp2f(x); }
__device__ __forceinline__ float fast_rcp(float x)  { return __builtin_amdgcn_rcpf(x); }
// u-domain pair silu: inputs u0,u1 (= c*x). outputs p = u*sigma = c*silu(x).
__device__ __forceinline__ void usilu2(float u0, float u1, float& p0, float& p1) {
  const float d0 = 1.0f + fast_exp2(u0);
  const float d1 = 1.0f + fast_exp2(u1);
  const float r  = fast_rcp(d0 * d1);
  p0 = u0 * d1 * r;
  p1 = u1 * d0 * r;
}
__device__ __forceinline__ half2v pkh(float a, float b) {
  return __builtin_bit_cast(half2v, __builtin_amdgcn_cvt_pkrtz(a, b));
}

union H8 { half8 v8; half2v v2[4]; half4v v4[2]; };
union H4 { half4v v4; half2v v2[2]; };

__global__ __launch_bounds__(256, 3) void mlp_kernel(
    const int* __restrict__ tix, const float* __restrict__ rho,
    const float* __restrict__ emb, const float* __restrict__ W0,
    const float* __restrict__ b0, const float* __restrict__ W1,
    const float* __restrict__ b1, const float* __restrict__ Wout,
    const float* __restrict__ bout, float* __restrict__ out, int ntiles)
{
  // Weight staging (init only) unions with the DOUBLE-BUFFERED per-wave H.
  // stage = 16384 B; H[4 waves][2 bufs][16][72] = 18432 B. Union = 18432 B.
  __shared__ __align__(16) union {
    _Float16 stage[2][2][4][64][8];
    _Float16 H[4][2][16][72];       // stride 144 B rows -> 2-way banks (free)
  } shA;

  const int tid  = threadIdx.x;
  const int wid  = tid >> 6;
  const int lane = tid & 63;
  const int m    = lane & 15;
  const int q    = lane >> 4;

  _Float16 (*Hb2)[16][72] = shA.H[wid];   // [2][16][72]

  // ---- init: wave 0 builds the swizzled weight fragments ----
  // content B[k=s*32+q*8+j][n=t*16+m]; same lane layout serves as A-op
  // (=> W^T) or B-op. L0 feature rows PERMUTED: k-window 32..63 =
  // [cos1..8|sin1..8|rho,b0(1.0),0pad]. L0 fragments PRE-SCALED by c.
  if (wid == 0) {
#pragma unroll
    for (int t = 0; t < 4; ++t) {
#pragma unroll
      for (int s = 0; s < 2; ++s) {
        half8 f0, f1;
#pragma unroll
        for (int j = 0; j < 8; ++j) {
          const int k = s * 32 + q * 8 + j;
          const int n = t * 16 + m;
          float v0;
          if (k < 32) {
            v0 = W0[k * 64 + n];
          } else {
            const int kn = k - 32;
            v0 = (kn < 16) ? W0[(33 + kn) * 64 + n]
               : (kn == 16) ? W0[32 * 64 + n]
               : (kn == 17) ? b0[n] : 0.0f;
          }
          f0[j] = (_Float16)(CSCL * v0);
          f1[j] = (_Float16)W1[k * 64 + n];   // W1 UNSCALED (c rides through p)
        }
        *(half8*)&shA.stage[0][s][t][lane][0] = f0;
        *(half8*)&shA.stage[1][s][t][lane][0] = f1;
      }
    }
  }

  // ---- persistent epilogue constants (SWAPPED L1 layout) ----
  // lane (q,m) owns hidden h = t*16 + q*4 + r.
  f32x4 bq1acc[4];
  f32x4 woutq[4];
#pragma unroll
  for (int t = 0; t < 4; ++t) {
    const f32x4 bv = *(const f32x4*)(b1 + t * 16 + q * 4);
    const f32x4 wv = *(const f32x4*)(Wout + t * 16 + q * 4);
#pragma unroll
    for (int r = 0; r < 4; ++r) {
      bq1acc[t][r] = CSCL * bv[r];
      woutq[t][r]  = NLN2 * wv[r];
    }
  }
  const float boutBL = bout[0] + BASE_LOGIT;

  __syncthreads();   // staged weights visible

  half8 w0A[4], w0B[4], w1A[4], w1B[4];
#pragma unroll
  for (int t = 0; t < 4; ++t) {
    w0A[t] = *(const half8*)&shA.stage[0][0][t][lane][0];
    w0B[t] = *(const half8*)&shA.stage[0][1][t][lane][0];
    w1A[t] = *(const half8*)&shA.stage[1][0][t][lane][0];
    w1B[t] = *(const half8*)&shA.stage[1][1][t][lane][0];
  }

  __syncthreads();   // stage reads done; H may overwrite

  const f32x4 z = {0.0f, 0.0f, 0.0f, 0.0f};
  const int S = gridDim.x * 4;

  int tg = blockIdx.x * 4 + wid;
  if (tg >= ntiles) return;          // after both barriers: safe
  const int lim = ntiles - 1;

  // ---- phase1: feat -> L0 -> silu -> H[wb]  (tile defined by rhp, X0) ----
  auto phase1 = [&](float rhp, half8 X0v, int wb) {
    const float rev = 0.5f * rhp;  // v_sin/v_cos take revolutions
    const float c1  = __builtin_amdgcn_cosf(rev);
    const float s1f = __builtin_amdgcn_sinf(rev);
    const float tc  = 2.0f * c1;
    const float x1v = (q == 0) ? c1 : ((q == 1) ? s1f : 0.0f);
    const float x0v = (q == 0) ? 1.0f : 0.0f;
    const float x2v = tc * x1v - x0v;
    const float x3v = tc * x2v - x1v;
    const float x4v = tc * x3v - x2v;
    const float x5v = tc * x4v - x3v;
    const float x6v = tc * x5v - x4v;
    const float x7v = tc * x6v - x5v;
    const float x8v = tc * x7v - x6v;
    H8 X1;
    X1.v2[0] = (q == 2) ? pkh(rhp, 1.0f) : pkh(x1v, x2v);  // q==2: (rho, b0-slot)
    X1.v2[1] = pkh(x3v, x4v);
    X1.v2[2] = pkh(x5v, x6v);
    X1.v2[3] = pkh(x7v, x8v);

    f32x4 acc[4];
#pragma unroll
    for (int t = 0; t < 4; ++t) {
      f32x4 a = __builtin_amdgcn_mfma_f32_16x16x32_f16(w0A[t], X0v, z, 0, 0, 0);
      a = __builtin_amdgcn_mfma_f32_16x16x32_f16(w0B[t], X1.v8, a, 0, 0, 0);
      acc[t] = a;
    }
#pragma unroll
    for (int t = 0; t < 4; ++t) {
      float p0, p1, p2, p3;
      usilu2(acc[t][0], acc[t][1], p0, p1);
      usilu2(acc[t][2], acc[t][3], p2, p3);
      H4 hh;
      hh.v2[0] = pkh(p0, p1);
      hh.v2[1] = pkh(p2, p3);
      *(half4v*)&Hb2[wb][m][t * 16 + q * 4] = hh.v4;
    }
  };

  // ---- phase2: Y(H[rb]) -> L1 -> silu -> dot -> store(tile tgS, ic) ----
  auto phase2 = [&](int rb, int tgS, int icS) {
    const half8 Y0 = *(const half8*)&Hb2[rb][m][q * 8];
    const half8 Y1 = *(const half8*)&Hb2[rb][m][32 + q * 8];
    f32x4 acc[4];
#pragma unroll
    for (int t = 0; t < 4; ++t) {
      f32x4 a = __builtin_amdgcn_mfma_f32_16x16x32_f16(w1A[t], Y0, bq1acc[t], 0, 0, 0);
      a = __builtin_amdgcn_mfma_f32_16x16x32_f16(w1B[t], Y1, a, 0, 0, 0);
      acc[t] = a;
    }
    float dA = 0.0f, dB = 0.0f;
#pragma unroll
    for (int t = 0; t < 4; ++t) {
      float p0, p1, p2, p3;
      usilu2(acc[t][0], acc[t][1], p0, p1);
      usilu2(acc[t][2], acc[t][3], p2, p3);
      dA = fmaf(p0, woutq[t][0], dA);
      dB = fmaf(p1, woutq[t][1], dB);
      dA = fmaf(p2, woutq[t][2], dA);
      dB = fmaf(p3, woutq[t][3], dB);
    }
    float dot = dA + dB;
    dot += __shfl_xor(dot, 16, 64);
    dot += __shfl_xor(dot, 32, 64);
    const float theta = fast_rcp(1.0f + fast_exp2(-LOG2E * (dot + boutBL)));
    const float val = (icS == 0) ? IC_VAL : theta * CSANMAX;
    if (q == 0) out[tgS * 16 + m] = val;
  };

  // ---- prologue: fill the pipe with tile tg ----
  int   tC = tix[tg * 16 + m];
  float rC = rho[tg * 16 + m];
  const int tg1 = min(tg + S, lim);
  int   tN = tix[tg1 * 16 + m];
  float rN = rho[tg1 * 16 + m];
  const int tg2 = min(tg + 2 * S, lim);
  int   tNN0 = tix[tg2 * 16 + m];
  float rNN0 = rho[tg2 * 16 + m];

  H8 X0C;
  {
    const int idx = min(max(tC - 1, 0), 510);
    const float* e = emb + (size_t)idx * 32 + q * 8;
    const f32x4 e0 = *(const f32x4*)e;
    const f32x4 e1 = *(const f32x4*)(e + 4);
    X0C.v2[0] = pkh(e0[0], e0[1]); X0C.v2[1] = pkh(e0[2], e0[3]);
    X0C.v2[2] = pkh(e1[0], e1[1]); X0C.v2[3] = pkh(e1[2], e1[3]);
  }
  phase1(rC, X0C.v8, 0);
  int icP = tC, tgP = tg;
  {
    const int idx = min(max(tN - 1, 0), 510);
    const float* e = emb + (size_t)idx * 32 + q * 8;
    const f32x4 e0 = *(const f32x4*)e;
    const f32x4 e1 = *(const f32x4*)(e + 4);
    X0C.v2[0] = pkh(e0[0], e0[1]); X0C.v2[1] = pkh(e0[2], e0[3]);
    X0C.v2[2] = pkh(e1[0], e1[1]); X0C.v2[3] = pkh(e1[2], e1[3]);
  }
  tC = tN; rC = rN;
  tN = tNN0; rN = rNN0;

  int wbuf = 1;
  tg += S;

  // ---- steady state: phase2(prev tile) || phase1(current tile) ----
  while (tg < ntiles) {
    // prefetch tix/rho 2 tiles ahead (clamped, branchless)
    const int tgn2 = min(tg + 2 * S, lim);
    const int   tNN = tix[tgn2 * 16 + m];
    const float rNN = rho[tgn2 * 16 + m];
    // emb load for NEXT tile (tN arrived >=1 iteration ago)
    const int idxN = min(max(tN - 1, 0), 510);
    const float* ern = emb + (size_t)idxN * 32 + q * 8;
    const f32x4 eN0 = *(const f32x4*)ern;
    const f32x4 eN1 = *(const f32x4*)(ern + 4);

    phase2(wbuf ^ 1, tgP, icP);      // finish PREVIOUS tile (independent...)
    phase1(rC, X0C.v8, wbuf);        // ...of starting CURRENT tile

    icP = tC; tgP = tg;
    // pack next tile's emb (vmem slack = phase2+phase1 above)
    X0C.v2[0] = pkh(eN0[0], eN0[1]); X0C.v2[1] = pkh(eN0[2], eN0[3]);
    X0C.v2[2] = pkh(eN1[0], eN1[1]); X0C.v2[3] = pkh(eN1[2], eN1[3]);
    tC = tN; rC = rN;
    tN = tNN; rN = rNN;
    wbuf ^= 1;
    tg += S;
  }

  // ---- epilogue: drain the last tile ----
  phase2(wbuf ^ 1, tgP, icP);
}

extern "C" void kernel_launch(void* const* d_in, const int* in_sizes, int n_in,
                              void* d_out, int out_size, void* d_ws, size_t ws_size,
                              hipStream_t stream) {
  const int*   tix  = (const int*)d_in[0];
  const float* rho  = (const float*)d_in[1];
  const float* emb  = (const float*)d_in[2];
  const float* W0   = (const float*)d_in[3];
  const float* b0   = (const float*)d_in[4];
  const float* W1   = (const float*)d_in[5];
  const float* b1   = (const float*)d_in[6];
  const float* Wout = (const float*)d_in[7];
  const float* bout = (const float*)d_in[8];
  float* outp = (float*)d_out;

  const int n      = in_sizes[0];    // 2,000,000 (divisible by 16)
  const int ntiles = n / 16;         // 125,000 tiles of 16 points

  // 4-wave blocks, 18432 B LDS. Grid 1024 (R3's measured winner vs 2048).
  int grid = 1024;
  const int maxg = (ntiles + 3) / 4;
  if (grid > maxg) grid = maxg;
  mlp_kernel<<<dim3(grid), dim3(256), 0, stream>>>(
      tix, rho, emb, W0, b0, W1, b1, Wout, bout, outp, ntiles);
}